// Round 1
// baseline (8187.782 us; speedup 1.0000x reference)
//
#include <hip/hip_runtime.h>

#define D 128
#define C 40

__global__ void deg_init_kernel(float* __restrict__ deg, int n) {
    int i = blockIdx.x * blockDim.x + threadIdx.x;
    if (i < n) deg[i] = 1.0f;  // self-loop contributes 1
}

__global__ void deg_count_kernel(const int* __restrict__ dst, float* __restrict__ deg, int E) {
    int e = blockIdx.x * blockDim.x + threadIdx.x;
    if (e < E) atomicAdd(&deg[dst[e]], 1.0f);
}

__global__ void rsqrt_kernel(float* __restrict__ deg, int n) {
    int i = blockIdx.x * blockDim.x + threadIdx.x;
    if (i < n) deg[i] = rsqrtf(deg[i]);  // deg >= 1 always
}

// xout[i,:] = dis[i]^2 * xin[i,:]   (self-loop term; also serves as the zero-init)
__global__ void self_init_kernel(const float* __restrict__ xin, const float* __restrict__ dis,
                                 float* __restrict__ xout, int n) {
    long long gid = (long long)blockIdx.x * blockDim.x + threadIdx.x;
    long long total = (long long)n * (D / 4);
    if (gid >= total) return;
    int node = (int)(gid >> 5);  // D/4 = 32 float4 per node
    float s = dis[node];
    float sc = s * s;
    const float4* xi = (const float4*)xin;
    float4* xo = (float4*)xout;
    float4 v = xi[gid];
    v.x *= sc; v.y *= sc; v.z *= sc; v.w *= sc;
    xo[gid] = v;
}

// xout[dst,:] += dis[src]*dis[dst] * xin[src,:]   (32 threads per edge, float4 each)
__global__ void scatter_kernel(const int* __restrict__ src, const int* __restrict__ dst,
                               const float* __restrict__ dis,
                               const float* __restrict__ xin, float* __restrict__ xout, int E) {
    long long gid = (long long)blockIdx.x * blockDim.x + threadIdx.x;
    int e = (int)(gid >> 5);
    if (e >= E) return;
    int t = (int)(gid & 31);
    int s = src[e];
    int d = dst[e];
    float nm = dis[s] * dis[d];
    const float4* xs = (const float4*)(xin + (size_t)s * D);
    float4 v = xs[t];
    float* xo = xout + (size_t)d * D + t * 4;
    atomicAdd(xo + 0, v.x * nm);
    atomicAdd(xo + 1, v.y * nm);
    atomicAdd(xo + 2, v.z * nm);
    atomicAdd(xo + 3, v.w * nm);
}

// logits = x @ W + b ; out = log_softmax(logits, axis=1). One thread per node.
__global__ void head_kernel(const float* __restrict__ x, const float* __restrict__ W,
                            const float* __restrict__ b, float* __restrict__ out, int n) {
    int i = blockIdx.x * blockDim.x + threadIdx.x;
    if (i >= n) return;
    float acc[C];
#pragma unroll
    for (int c = 0; c < C; ++c) acc[c] = b[c];
    const float* xr = x + (size_t)i * D;
    for (int d = 0; d < D; ++d) {
        float xv = xr[d];
#pragma unroll
        for (int c = 0; c < C; ++c) acc[c] += xv * W[d * C + c];
    }
    float m = acc[0];
#pragma unroll
    for (int c = 1; c < C; ++c) m = fmaxf(m, acc[c]);
    float ssum = 0.0f;
#pragma unroll
    for (int c = 0; c < C; ++c) ssum += expf(acc[c] - m);
    float ls = logf(ssum);
    float* o = out + (size_t)i * C;
#pragma unroll
    for (int c = 0; c < C; ++c) o[c] = acc[c] - m - ls;
}

extern "C" void kernel_launch(void* const* d_in, const int* in_sizes, int n_in,
                              void* d_out, int out_size, void* d_ws, size_t ws_size,
                              hipStream_t stream) {
    const float* x  = (const float*)d_in[0];
    const int*   ei = (const int*)d_in[1];   // [2, E] flat: row0 = src, row1 = dst
    const float* W  = (const float*)d_in[2]; // [D, C] row-major
    const float* b  = (const float*)d_in[3];
    float* out = (float*)d_out;

    const int N = in_sizes[0] / D;
    const int E = in_sizes[1] / 2;
    const int* src = ei;
    const int* dst = ei + E;

    // Workspace carve-up: dis[N] | buf0[N*D] | buf1[N*D]   (~103 MB total)
    float* dis = (float*)d_ws;
    size_t npad = ((size_t)N + 255) & ~(size_t)255;
    float* buf0 = dis + npad;
    float* buf1 = buf0 + (size_t)N * D;

    const int TB = 256;
    int nb_n = (N + TB - 1) / TB;
    int nb_e = (E + TB - 1) / TB;
    long long node_thr = (long long)N * (D / 4);
    int nb_nf = (int)((node_thr + TB - 1) / TB);
    long long edge_thr = (long long)E * (D / 4);
    int nb_ef = (int)((edge_thr + TB - 1) / TB);

    // degree + rsqrt
    deg_init_kernel<<<nb_n, TB, 0, stream>>>(dis, N);
    deg_count_kernel<<<nb_e, TB, 0, stream>>>(dst, dis, E);
    rsqrt_kernel<<<nb_n, TB, 0, stream>>>(dis, N);

    // hop 1: x -> buf0
    self_init_kernel<<<nb_nf, TB, 0, stream>>>(x, dis, buf0, N);
    scatter_kernel<<<nb_ef, TB, 0, stream>>>(src, dst, dis, x, buf0, E);
    // hop 2: buf0 -> buf1
    self_init_kernel<<<nb_nf, TB, 0, stream>>>(buf0, dis, buf1, N);
    scatter_kernel<<<nb_ef, TB, 0, stream>>>(src, dst, dis, buf0, buf1, E);
    // hop 3: buf1 -> buf0
    self_init_kernel<<<nb_nf, TB, 0, stream>>>(buf1, dis, buf0, N);
    scatter_kernel<<<nb_ef, TB, 0, stream>>>(src, dst, dis, buf1, buf0, E);

    // head: logits + log_softmax
    head_kernel<<<nb_n, TB, 0, stream>>>(buf0, W, b, out, N);
}

// Round 2
// 579.893 us; speedup vs baseline: 14.1195x; 14.1195x over previous
//
#include <hip/hip_runtime.h>

#define D 128
#define C 40
#define SCAN_B 256

// ---- init: cnt=0, cursor=0 ----
__global__ void zero2_kernel(int* __restrict__ cnt, int* __restrict__ cursor, int n) {
    int i = blockIdx.x * blockDim.x + threadIdx.x;
    if (i < n) { cnt[i] = 0; cursor[i] = 0; }
}

// ---- histogram of dst ----
__global__ void count_kernel(const int* __restrict__ dst, int* __restrict__ cnt, int E) {
    int e = blockIdx.x * blockDim.x + threadIdx.x;
    if (e < E) atomicAdd(&cnt[dst[e]], 1);
}

// ---- dis[i] = rsqrt(1 + cnt[i]) ----
__global__ void dis_kernel(const int* __restrict__ cnt, float* __restrict__ dis, int n) {
    int i = blockIdx.x * blockDim.x + threadIdx.x;
    if (i < n) dis[i] = rsqrtf(1.0f + (float)cnt[i]);
}

// ---- 3-kernel exclusive scan over cnt -> rowptr ----
__global__ void scan_block_kernel(const int* __restrict__ cnt, int* __restrict__ rowptr,
                                  int* __restrict__ bsum, int n) {
    __shared__ int s[SCAN_B];
    int i = blockIdx.x * SCAN_B + threadIdx.x;
    int v = (i < n) ? cnt[i] : 0;
    s[threadIdx.x] = v;
    __syncthreads();
    for (int off = 1; off < SCAN_B; off <<= 1) {
        int t = (threadIdx.x >= off) ? s[threadIdx.x - off] : 0;
        __syncthreads();
        s[threadIdx.x] += t;
        __syncthreads();
    }
    if (i < n) rowptr[i] = s[threadIdx.x] - v;  // exclusive within block
    if (threadIdx.x == SCAN_B - 1) bsum[blockIdx.x] = s[SCAN_B - 1];
}

__global__ void scan_bsum_kernel(int* __restrict__ bsum, int nb) {
    __shared__ int s[512];
    int v = (threadIdx.x < nb) ? bsum[threadIdx.x] : 0;
    s[threadIdx.x] = v;
    __syncthreads();
    for (int off = 1; off < 512; off <<= 1) {
        int t = (threadIdx.x >= off) ? s[threadIdx.x - off] : 0;
        __syncthreads();
        s[threadIdx.x] += t;
        __syncthreads();
    }
    if (threadIdx.x < nb) bsum[threadIdx.x] = s[threadIdx.x] - v;  // exclusive
}

__global__ void add_off_kernel(int* __restrict__ rowptr, const int* __restrict__ bsum,
                               int n, int E) {
    int i = blockIdx.x * blockDim.x + threadIdx.x;
    if (i < n) rowptr[i] += bsum[i >> 8];
    if (i == 0) rowptr[n] = E;
}

// ---- fill CSR: srcs + precomputed edge norms ----
__global__ void fill_kernel(const int* __restrict__ src, const int* __restrict__ dst,
                            const int* __restrict__ rowptr, int* __restrict__ cursor,
                            const float* __restrict__ dis,
                            int* __restrict__ srcs, float* __restrict__ wnorm, int E) {
    int e = blockIdx.x * blockDim.x + threadIdx.x;
    if (e >= E) return;
    int s = src[e];
    int d = dst[e];
    int pos = rowptr[d] + atomicAdd(&cursor[d], 1);
    srcs[pos] = s;
    wnorm[pos] = dis[s] * dis[d];
}

// ---- one propagation hop: gather by destination, no atomics ----
// 32 lanes per node, one float4 per lane (D=128). Block = 256 -> 8 nodes.
__global__ void gather_hop_kernel(const float* __restrict__ xin, float* __restrict__ xout,
                                  const int* __restrict__ rowptr, const int* __restrict__ srcs,
                                  const float* __restrict__ wnorm, const float* __restrict__ dis,
                                  int n) {
    int node = blockIdx.x * 8 + (threadIdx.x >> 5);
    int t = threadIdx.x & 31;
    if (node >= n) return;
    const float4* xi = (const float4*)xin;
    float s = dis[node];
    float4 acc = xi[(size_t)node * 32 + t];
    float sc = s * s;
    acc.x *= sc; acc.y *= sc; acc.z *= sc; acc.w *= sc;
    int beg = rowptr[node];
    int end = rowptr[node + 1];
    for (int e = beg; e < end; ++e) {
        int sv = srcs[e];
        float w = wnorm[e];
        float4 v = xi[(size_t)sv * 32 + t];
        acc.x += w * v.x; acc.y += w * v.y; acc.z += w * v.z; acc.w += w * v.w;
    }
    ((float4*)xout)[(size_t)node * 32 + t] = acc;
}

// ---- head: logits + log_softmax, one thread per node ----
__global__ void head_kernel(const float* __restrict__ x, const float* __restrict__ W,
                            const float* __restrict__ b, float* __restrict__ out, int n) {
    int i = blockIdx.x * blockDim.x + threadIdx.x;
    if (i >= n) return;
    float acc[C];
#pragma unroll
    for (int c = 0; c < C; ++c) acc[c] = b[c];
    const float* xr = x + (size_t)i * D;
    for (int d = 0; d < D; ++d) {
        float xv = xr[d];
#pragma unroll
        for (int c = 0; c < C; ++c) acc[c] += xv * W[d * C + c];
    }
    float m = acc[0];
#pragma unroll
    for (int c = 1; c < C; ++c) m = fmaxf(m, acc[c]);
    float ssum = 0.0f;
#pragma unroll
    for (int c = 0; c < C; ++c) ssum += expf(acc[c] - m);
    float ls = logf(ssum);
    float* o = out + (size_t)i * C;
#pragma unroll
    for (int c = 0; c < C; ++c) o[c] = acc[c] - m - ls;
}

extern "C" void kernel_launch(void* const* d_in, const int* in_sizes, int n_in,
                              void* d_out, int out_size, void* d_ws, size_t ws_size,
                              hipStream_t stream) {
    const float* x  = (const float*)d_in[0];
    const int*   ei = (const int*)d_in[1];   // [2, E] flat: row0 = src, row1 = dst
    const float* W  = (const float*)d_in[2]; // [D, C] row-major
    const float* b  = (const float*)d_in[3];
    float* out = (float*)d_out;

    const int N = in_sizes[0] / D;
    const int E = in_sizes[1] / 2;
    const int* src = ei;
    const int* dst = ei + E;

    // Workspace carve-up (all 256B-aligned chunks):
    // dis[N] f32 | cnt[N] i32 | cursor[N] i32 | rowptr[N+1] i32 | bsum[512] i32 |
    // srcs[E] i32 | wnorm[E] f32 | buf0[N*D] f32 | buf1[N*D] f32      (~117 MB)
    size_t npad = ((size_t)N + 256) & ~(size_t)255;
    char* p = (char*)d_ws;
    float* dis    = (float*)p;            p += npad * 4;
    int*   cnt    = (int*)p;              p += npad * 4;
    int*   cursor = (int*)p;              p += npad * 4;
    int*   rowptr = (int*)p;              p += npad * 4;
    int*   bsum   = (int*)p;              p += 512 * 4;
    size_t epad = ((size_t)E + 255) & ~(size_t)255;
    int*   srcs   = (int*)p;              p += epad * 4;
    float* wnorm  = (float*)p;            p += epad * 4;
    float* buf0   = (float*)p;            p += (size_t)N * D * 4;
    float* buf1   = (float*)p;

    const int TB = 256;
    int nb_n = (N + TB - 1) / TB;
    int nb_e = (E + TB - 1) / TB;
    int nb_scan = (N + SCAN_B - 1) / SCAN_B;  // 391 <= 512

    // ---- CSR build ----
    zero2_kernel<<<nb_n, TB, 0, stream>>>(cnt, cursor, N);
    count_kernel<<<nb_e, TB, 0, stream>>>(dst, cnt, E);
    dis_kernel<<<nb_n, TB, 0, stream>>>(cnt, dis, N);
    scan_block_kernel<<<nb_scan, SCAN_B, 0, stream>>>(cnt, rowptr, bsum, N);
    scan_bsum_kernel<<<1, 512, 0, stream>>>(bsum, nb_scan);
    add_off_kernel<<<nb_n, TB, 0, stream>>>(rowptr, bsum, N, E);
    fill_kernel<<<nb_e, TB, 0, stream>>>(src, dst, rowptr, cursor, dis, srcs, wnorm, E);

    // ---- K=3 hops, ping-pong ----
    int nb_g = (N + 7) / 8;
    gather_hop_kernel<<<nb_g, TB, 0, stream>>>(x,    buf0, rowptr, srcs, wnorm, dis, N);
    gather_hop_kernel<<<nb_g, TB, 0, stream>>>(buf0, buf1, rowptr, srcs, wnorm, dis, N);
    gather_hop_kernel<<<nb_g, TB, 0, stream>>>(buf1, buf0, rowptr, srcs, wnorm, dis, N);

    // ---- head ----
    head_kernel<<<nb_n, TB, 0, stream>>>(buf0, W, b, out, N);
}